// Round 7
// baseline (498.016 us; speedup 1.0000x reference)
//
#include <hip/hip_runtime.h>
#include <hip/hip_bf16.h>

// Attention_50946902065218: Bahdanau-style attention
// B=256, L=196, E=2048, D=1024, A=512
// Pipeline:
//  k_wepack: We fp32 -> bf16, BK=64 layout [kb][n][slot^swz(n)][e], swizzle
//            baked in so linear global_load_lds staging is conflict-free
//  k_bias2 : bias2[b][a] = be[a] + bd[a] + dec[b]@Wd[:,a]
//  k_gemm_score (v7): 256x256 tile, BK=64, 8 waves (2x4), wave tile 128x64
//     (m198-geometry). 2-phase dbuf: issue A-loads+stageB(t+1) before
//     compute(t), convert+ds_write after, one barrier per K-tile.
//     Partial wf-dot -> scoresP[2][M]
//  k_softmax: sum 2 partials + mask + softmax over L -> alpha
//  k_awe (v4): 4-way L-split (1024 blocks) -> aweP[4], then k_awecomb

#define B_ 256
#define L_ 196
#define E_ 2048
#define D_ 1024
#define A_ 512
#define M_TOT (B_ * L_)   // 50176 = 196 * 256

typedef __attribute__((ext_vector_type(8))) short bf16x8;
typedef __attribute__((ext_vector_type(4))) float f32x4;

static __device__ __forceinline__ unsigned short f2bf(float f) {
    union { float f; unsigned u; } u{f};
    unsigned r = u.u + 0x7fffu + ((u.u >> 16) & 1u);   // RNE
    return (unsigned short)(r >> 16);
}

static __device__ __forceinline__ unsigned int pk2(float x, float y) {
    __hip_bfloat162 h = __float22bfloat162_rn(float2{x, y});   // v_cvt_pk_bf16_f32
    return *reinterpret_cast<unsigned int*>(&h);
}

static __device__ __forceinline__ void gload_lds16(const void* g, void* l) {
    __builtin_amdgcn_global_load_lds(
        (const __attribute__((address_space(1))) unsigned int*)g,
        (__attribute__((address_space(3))) unsigned int*)l, 16, 0, 0);
}

// ---------------- kernel 0a: pack We (E x A fp32) -> WeP bf16 -----------------
// Element (k, n): kb=k>>6, ks=(k>>5)&1, kg=(k>>3)&3, e=k&7.
// slot = ks*4+kg (8 x 16B slots per n-row of 128B); stored slot' = slot^(n&7).
// Index (shorts) = kb*32768 + n*64 + slot'*8 + e. A fragment read (16 lanes,
// n=base+lr, fixed slot) then spreads over all 8 slots -> 2 lanes/bank (free).
__global__ __launch_bounds__(256) void k_wepack(const float* __restrict__ We,
                                                unsigned short* __restrict__ WeP) {
    int i = blockIdx.x * 256 + threadIdx.x;       // source index over 2048*512
    int k = i >> 9, n = i & 511;
    int kb = k >> 6, slot = (k >> 3) & 7, e = k & 7;
    int slotE = slot ^ (n & 7);
    WeP[(kb << 15) + (n << 6) + (slotE << 3) + e] = f2bf(We[i]);
}

// ---------------- kernel 0b: bias2 = be + bd + dec @ Wd ----------------------
__global__ __launch_bounds__(256) void k_bias2(const float* __restrict__ dec,
                                               const float* __restrict__ Wd,
                                               const float* __restrict__ be,
                                               const float* __restrict__ bd,
                                               float* __restrict__ bias2) {
    int b = blockIdx.x, t = threadIdx.x;
    __shared__ float ds[D_];
    for (int i = t; i < D_; i += 256) ds[i] = dec[b * D_ + i];
    __syncthreads();
    for (int a0 = 0; a0 < A_; a0 += 256) {
        int a = a0 + t;
        float acc = 0.f;
        #pragma unroll 8
        for (int d = 0; d < D_; d++) acc += ds[d] * Wd[d * A_ + a];
        bias2[b * A_ + a] = acc + be[a] + bd[a];
    }
}

// ---------------- kernel 1: fused GEMM + tanh + wf-dot -----------------------
// 392 blocks (196 mt x 2 nt, XCD-chunked: 392 = 8*49), 512 threads, 8 waves
// (2 wm x 4 wn), wave tile 128x64, acc[8][4]. BK=64, 32 K-tiles.
__global__ __launch_bounds__(512, 2) void k_gemm_score(
        const float* __restrict__ enc,
        const unsigned short* __restrict__ WeP,
        const float* __restrict__ bias2,
        const float* __restrict__ wf,
        float* __restrict__ scoresP) {
    __shared__ __align__(16) unsigned short aL[2][256 * 64];  // 32 KB each
    __shared__ __align__(16) unsigned short bL[2][256 * 64];  // 32 KB each
    __shared__ float score_lds[8][128];

    const int tid = threadIdx.x;
    // bijective XCD-chunked swizzle: xcd = raw&7 owns 49 consecutive wg;
    // nt-pairs (same mt) are adjacent -> A-slab L2 reuse within an XCD.
    const int raw = blockIdx.x;
    const int wg = (raw & 7) * 49 + (raw >> 3);
    const int mt = wg >> 1, nt = wg & 1;
    const int m0 = mt * 256;

    const int lane = tid & 63;
    const int wid = tid >> 6;
    const int wm = wid >> 2, wn = wid & 3;
    const int kg = lane >> 4, lr = lane & 15;

    // A staging: thread -> row ar = tid>>1 (2 thr/row), k-half kh = tid&1
    const int ar = tid >> 1, kh = tid & 1;
    const float* aSrc = enc + (size_t)(m0 + ar) * E_ + kh * 32;

    // B staging: 4 x gload_lds16/thread, linear 32KB K-slice (pre-swizzled)
    const unsigned short* bSrc = WeP + nt * 16384 + tid * 8;

    auto stageB = [&](int kb, int buf) {
        const unsigned short* s = bSrc + (kb << 15);
        #pragma unroll
        for (int c = 0; c < 4; c++)
            gload_lds16(s + c * 4096, &bL[buf][c * 4096 + tid * 8]);
    };
    auto loadA = [&](float4 (&v)[8], int kb) {
        const float* p = aSrc + (kb << 6);
        #pragma unroll
        for (int c = 0; c < 8; c++)
            v[c] = *reinterpret_cast<const float4*>(p + c * 4);
    };
    auto writeA = [&](const float4 (&v)[8], int buf) {
        #pragma unroll
        for (int g = 0; g < 4; g++) {           // k-group within half
            uint4 q;
            q.x = pk2(v[2 * g].x, v[2 * g].y);
            q.y = pk2(v[2 * g].z, v[2 * g].w);
            q.z = pk2(v[2 * g + 1].x, v[2 * g + 1].y);
            q.w = pk2(v[2 * g + 1].z, v[2 * g + 1].w);
            int slot = (kh * 4 + g) ^ (ar & 7);
            *reinterpret_cast<uint4*>(&aL[buf][ar * 64 + slot * 8]) = q;
        }
    };

    f32x4 acc[8][4];
    #pragma unroll
    for (int i = 0; i < 8; i++)
        #pragma unroll
        for (int j = 0; j < 4; j++) acc[i][j] = (f32x4){0.f, 0.f, 0.f, 0.f};

    auto computeTile = [&](int buf) {
        #pragma unroll
        for (int ks = 0; ks < 2; ks++) {
            bf16x8 bfr[4];
            #pragma unroll
            for (int j = 0; j < 4; j++) {
                int n = wn * 64 + j * 16 + lr;
                int slot = (ks * 4 + kg) ^ (n & 7);
                bfr[j] = *reinterpret_cast<const bf16x8*>(
                    &bL[buf][n * 64 + slot * 8]);
            }
            #pragma unroll
            for (int i = 0; i < 8; i++) {
                int row = wm * 128 + i * 16 + lr;
                int slot = (ks * 4 + kg) ^ (row & 7);
                bf16x8 af = *reinterpret_cast<const bf16x8*>(
                    &aL[buf][row * 64 + slot * 8]);
                #pragma unroll
                for (int j = 0; j < 4; j++)
                    acc[i][j] = __builtin_amdgcn_mfma_f32_16x16x32_bf16(
                        af, bfr[j], acc[i][j], 0, 0, 0);
            }
        }
    };

    // --- prologue: tile 0 staged, A(0) through regs ---
    float4 av[8];
    loadA(av, 0);
    __builtin_amdgcn_sched_barrier(0);
    stageB(0, 0);
    __builtin_amdgcn_sched_barrier(0);
    writeA(av, 0);                      // compiler waits on av's loads
    __syncthreads();                    // drains gloads + ds_writes

    int buf = 0;
    for (int kb = 0; kb < 32; kb++) {
        if (kb < 31) {
            loadA(av, kb + 1);          // HBM latency hides under compute
            __builtin_amdgcn_sched_barrier(0);
            stageB(kb + 1, buf ^ 1);    // L2-resident, hides under compute
            __builtin_amdgcn_sched_barrier(0);
        }
        computeTile(buf);
        __builtin_amdgcn_sched_barrier(0);
        if (kb < 31) writeA(av, buf ^ 1);
        __syncthreads();                // vmcnt(0)+lgkmcnt(0)+barrier
        buf ^= 1;
    }

    // --- epilogue: tanh + wf dot over this block's 256 cols -> partials ---
    #pragma unroll
    for (int i = 0; i < 8; i++) {
        #pragma unroll
        for (int r = 0; r < 4; r++) {
            int Rw = i * 16 + kg * 4 + r;   // C/D: col=lane&15, row=(lane>>4)*4+reg
            int gm = m0 + wm * 128 + Rw;
            int bg = gm / L_;
            float sum = 0.f;
            #pragma unroll
            for (int j = 0; j < 4; j++) {
                int C = nt * 256 + wn * 64 + j * 16 + lr;
                float x = acc[i][j][r] + bias2[bg * A_ + C];
                // fast tanh: 1 - 2/(e^{2x}+1)
                float ex = __expf(2.f * x);
                sum += wf[C] * (1.f - 2.f * __builtin_amdgcn_rcpf(ex + 1.f));
            }
            #pragma unroll
            for (int mk = 1; mk < 16; mk <<= 1) sum += __shfl_xor(sum, mk);
            if (lr == 0) score_lds[wid][Rw] = sum;
        }
    }
    __syncthreads();
    if (tid < 256) {
        int wmp = tid >> 7, rl = tid & 127;
        float s = score_lds[wmp * 4 + 0][rl] + score_lds[wmp * 4 + 1][rl] +
                  score_lds[wmp * 4 + 2][rl] + score_lds[wmp * 4 + 3][rl];
        scoresP[nt * M_TOT + m0 + wmp * 128 + rl] = s;
    }
}

// ---------------- kernel 2: sum partials + mask + softmax --------------------
__global__ __launch_bounds__(256) void k_softmax(const float* __restrict__ scoresP,
                                                 const int* __restrict__ mask,
                                                 const float* __restrict__ bfp,
                                                 float* __restrict__ alpha) {
    int b = blockIdx.x, t = threadIdx.x;
    float bfv = bfp[0];
    float v = -INFINITY;
    if (t < L_) {
        int idx = b * L_ + t;
        float sc = scoresP[idx] + scoresP[M_TOT + idx];
        v = (mask[idx] == 0) ? -1e9f : (sc + bfv);
    }
    __shared__ float redm[4], reds[4];
    float m = v;
    #pragma unroll
    for (int s = 1; s < 64; s <<= 1) m = fmaxf(m, __shfl_xor(m, s));
    int w = t >> 6;
    if ((t & 63) == 0) redm[w] = m;
    __syncthreads();
    m = fmaxf(fmaxf(redm[0], redm[1]), fmaxf(redm[2], redm[3]));
    float e = (t < L_) ? expf(v - m) : 0.f;
    float s = e;
    #pragma unroll
    for (int k = 1; k < 64; k <<= 1) s += __shfl_xor(s, k);
    if ((t & 63) == 0) reds[w] = s;
    __syncthreads();
    s = reds[0] + reds[1] + reds[2] + reds[3];
    if (t < L_) alpha[b * L_ + t] = e / s;
}

// ---------------- kernel 3: awe partials, 4-way L-split ----------------------
// 1024 blocks = (b, quarter q), 512 threads (one float4 of E each).
// Each block streams a contiguous 392KB slab; 4 blocks/CU = 32 waves/CU.
__global__ __launch_bounds__(512) void k_awe(const float* __restrict__ enc,
                                             const float* __restrict__ alpha,
                                             float* __restrict__ aweP) {
    int b = blockIdx.x >> 2, q = blockIdx.x & 3;
    int t = threadIdx.x;
    __shared__ float al[49];
    if (t < 49) al[t] = alpha[b * L_ + q * 49 + t];
    __syncthreads();
    const float* base = enc + ((size_t)b * L_ + (size_t)q * 49) * E_ + t * 4;
    float4 a0 = {0.f, 0.f, 0.f, 0.f}, a1 = a0, a2 = a0, a3 = a0;
    int l = 0;
    for (; l + 4 <= 48; l += 4) {
        float4 v0 = *reinterpret_cast<const float4*>(base + (size_t)l * E_);
        float4 v1 = *reinterpret_cast<const float4*>(base + (size_t)(l + 1) * E_);
        float4 v2 = *reinterpret_cast<const float4*>(base + (size_t)(l + 2) * E_);
        float4 v3 = *reinterpret_cast<const float4*>(base + (size_t)(l + 3) * E_);
        float c0 = al[l], c1 = al[l + 1], c2 = al[l + 2], c3 = al[l + 3];
        a0.x += c0 * v0.x; a0.y += c0 * v0.y; a0.z += c0 * v0.z; a0.w += c0 * v0.w;
        a1.x += c1 * v1.x; a1.y += c1 * v1.y; a1.z += c1 * v1.z; a1.w += c1 * v1.w;
        a2.x += c2 * v2.x; a2.y += c2 * v2.y; a2.z += c2 * v2.z; a2.w += c2 * v2.w;
        a3.x += c3 * v3.x; a3.y += c3 * v3.y; a3.z += c3 * v3.z; a3.w += c3 * v3.w;
    }
    {   // l = 48 tail
        float4 v0 = *reinterpret_cast<const float4*>(base + (size_t)48 * E_);
        float c0 = al[48];
        a0.x += c0 * v0.x; a0.y += c0 * v0.y; a0.z += c0 * v0.z; a0.w += c0 * v0.w;
    }
    float4 o;
    o.x = (a0.x + a1.x) + (a2.x + a3.x);
    o.y = (a0.y + a1.y) + (a2.y + a3.y);
    o.z = (a0.z + a1.z) + (a2.z + a3.z);
    o.w = (a0.w + a1.w) + (a2.w + a3.w);
    *reinterpret_cast<float4*>(aweP + ((size_t)q * B_ + b) * E_ + t * 4) = o;
}

// ---------------- kernel 4: combine awe partials ------------------------------
__global__ __launch_bounds__(256) void k_awecomb(const float* __restrict__ aweP,
                                                 float* __restrict__ awe) {
    int i = blockIdx.x * 256 + threadIdx.x;      // over B*E/4 float4
    const float4* p = reinterpret_cast<const float4*>(aweP);
    const size_t S = (size_t)B_ * E_ / 4;
    float4 r0 = p[i], r1 = p[S + i], r2 = p[2 * S + i], r3 = p[3 * S + i];
    float4 o;
    o.x = (r0.x + r1.x) + (r2.x + r3.x);
    o.y = (r0.y + r1.y) + (r2.y + r3.y);
    o.z = (r0.z + r1.z) + (r2.z + r3.z);
    o.w = (r0.w + r1.w) + (r2.w + r3.w);
    reinterpret_cast<float4*>(awe)[i] = o;
}

extern "C" void kernel_launch(void* const* d_in, const int* in_sizes, int n_in,
                              void* d_out, int out_size, void* d_ws, size_t ws_size,
                              hipStream_t stream) {
    const float* enc  = (const float*)d_in[0];
    const float* dec  = (const float*)d_in[1];
    const int*   mask = (const int*)d_in[2];
    const float* We   = (const float*)d_in[3];
    const float* be   = (const float*)d_in[4];
    const float* Wd   = (const float*)d_in[5];
    const float* bd   = (const float*)d_in[6];
    const float* wf   = (const float*)d_in[7];
    const float* bf   = (const float*)d_in[8];

    float* awe   = (float*)d_out;                  // [256][2048]
    float* alpha = awe + (size_t)B_ * E_;          // [256][196]

    char* ws = (char*)d_ws;
    unsigned short* WeP = (unsigned short*)ws;                        // 2 MB
    float* bias2   = (float*)(ws + (2u << 20));                       // 512 KB
    float* scoresP = (float*)(ws + (2u << 20) + (512u << 10));        // 401 KB
    float* aweP    = (float*)(ws + (3u << 20));                       // 8 MB

    hipLaunchKernelGGL(k_wepack, dim3((E_ * A_) / 256), dim3(256), 0, stream, We, WeP);
    hipLaunchKernelGGL(k_bias2, dim3(B_), dim3(256), 0, stream, dec, Wd, be, bd, bias2);
    hipLaunchKernelGGL(k_gemm_score, dim3(392), dim3(512), 0, stream,
                       enc, WeP, bias2, wf, scoresP);
    hipLaunchKernelGGL(k_softmax, dim3(B_), dim3(256), 0, stream, scoresP, mask, bf, alpha);
    hipLaunchKernelGGL(k_awe, dim3(B_ * 4), dim3(512), 0, stream, enc, alpha, aweP);
    hipLaunchKernelGGL(k_awecomb, dim3((B_ * E_ / 4) / 256), dim3(256), 0, stream, aweP, awe);
}